// Round 1
// baseline (117.918 us; speedup 1.0000x reference)
//
#include <hip/hip_runtime.h>
#include <hip/hip_bf16.h>

// Problem constants
#define NSEG   4480     // 70 * 64
#define ADIM   64
#define BDIM   16
#define NEDGE  65536
#define UPITCH 1088     // 1024 kernel-derived cols + 64 bias-derived cols
#define LPITCH 68       // LDS row pitch in floats (64 + 4 pad; 68*4B = 17*16B keeps float4 alignment)

// ---------------------------------------------------------------------------
// proj_kernel: U[a, c] = sum_j atom[a, j] * Brow(c)[j]
//   Brow(c) = kernel + (c&15)*4096 + (c>>4)*64   for c < 1024   (c = i*16 + b)
//           = bias   + (c-1024)*64               for c >= 1024  (bias term, col i)
// Tiles: 64 atoms x 64 cols, K = 64 (whole), fp32 vector ALU.
// LDS stored j-major (transposed) so fragment loads are ds_read_b128.
// ---------------------------------------------------------------------------
__global__ __launch_bounds__(256) void proj_kernel(
    const float* __restrict__ atom,
    const float* __restrict__ kern,
    const float* __restrict__ bias,
    float* __restrict__ U)
{
    __shared__ float As[64 * LPITCH];   // As[j][row]
    __shared__ float Bs[64 * LPITCH];   // Bs[j][crow]

    const int t      = threadIdx.x;
    const int a_base = blockIdx.x * 64;   // 0..69 -> atom tile
    const int c_base = blockIdx.y * 64;   // 0..16 -> col tile (tile 16 = bias)

    // ---- load A tile (64 rows x 64 floats), write transposed into LDS ----
#pragma unroll
    for (int k = 0; k < 4; ++k) {
        int id  = t + k * 256;            // 0..1023 float4-chunks
        int row = id >> 4;                // 0..63
        int j0  = (id & 15) * 4;          // 0..60
        float4 v = *(const float4*)(atom + (size_t)(a_base + row) * ADIM + j0);
        As[(j0 + 0) * LPITCH + row] = v.x;
        As[(j0 + 1) * LPITCH + row] = v.y;
        As[(j0 + 2) * LPITCH + row] = v.z;
        As[(j0 + 3) * LPITCH + row] = v.w;
    }
    // ---- load B tile ----
#pragma unroll
    for (int k = 0; k < 4; ++k) {
        int id   = t + k * 256;
        int crow = id >> 4;               // 0..63
        int j0   = (id & 15) * 4;
        int c    = c_base + crow;
        const float* bsrc = (c < 1024)
            ? (kern + (size_t)(c & 15) * 4096 + (size_t)(c >> 4) * 64)
            : (bias + (size_t)(c - 1024) * 64);
        float4 v = *(const float4*)(bsrc + j0);
        Bs[(j0 + 0) * LPITCH + crow] = v.x;
        Bs[(j0 + 1) * LPITCH + crow] = v.y;
        Bs[(j0 + 2) * LPITCH + crow] = v.z;
        Bs[(j0 + 3) * LPITCH + crow] = v.w;
    }
    __syncthreads();

    const int tx = t & 15;                // col group
    const int ty = t >> 4;                // row group
    const int a0 = ty * 4;
    const int c0 = tx * 4;

    float acc[4][4] = {};
#pragma unroll 8
    for (int j = 0; j < 64; ++j) {
        float4 av = *(const float4*)(As + j * LPITCH + a0);
        float4 bv = *(const float4*)(Bs + j * LPITCH + c0);
        acc[0][0] = fmaf(av.x, bv.x, acc[0][0]);
        acc[0][1] = fmaf(av.x, bv.y, acc[0][1]);
        acc[0][2] = fmaf(av.x, bv.z, acc[0][2]);
        acc[0][3] = fmaf(av.x, bv.w, acc[0][3]);
        acc[1][0] = fmaf(av.y, bv.x, acc[1][0]);
        acc[1][1] = fmaf(av.y, bv.y, acc[1][1]);
        acc[1][2] = fmaf(av.y, bv.z, acc[1][2]);
        acc[1][3] = fmaf(av.y, bv.w, acc[1][3]);
        acc[2][0] = fmaf(av.z, bv.x, acc[2][0]);
        acc[2][1] = fmaf(av.z, bv.y, acc[2][1]);
        acc[2][2] = fmaf(av.z, bv.z, acc[2][2]);
        acc[2][3] = fmaf(av.z, bv.w, acc[2][3]);
        acc[3][0] = fmaf(av.w, bv.x, acc[3][0]);
        acc[3][1] = fmaf(av.w, bv.y, acc[3][1]);
        acc[3][2] = fmaf(av.w, bv.z, acc[3][2]);
        acc[3][3] = fmaf(av.w, bv.w, acc[3][3]);
    }

#pragma unroll
    for (int r = 0; r < 4; ++r) {
        float4 o = make_float4(acc[r][0], acc[r][1], acc[r][2], acc[r][3]);
        *(float4*)(U + (size_t)(a_base + a0 + r) * UPITCH + c_base + c0) = o;
    }
}

// ---------------------------------------------------------------------------
// edge_kernel: one wave (64 lanes) per edge; lane i computes msg[e, i].
//   msg[e,i] = sum_b bond[e,b] * U[src, i*16+b]  +  U[src, 1024+i]
// Lane i reads its 16 U-weights as 4 contiguous float4 (whole wave streams
// the full 4KB U row, perfectly coalesced). Result scatter via atomicAdd.
// ---------------------------------------------------------------------------
__global__ __launch_bounds__(256) void edge_kernel(
    const float* __restrict__ bond,
    const int*   __restrict__ pair,
    const float* __restrict__ U,
    float*       __restrict__ out)
{
    const int t    = threadIdx.x;
    const int lane = t & 63;
    const int e    = blockIdx.x * 4 + (t >> 6);

    const int dst = pair[(size_t)e * 2 + 0];
    const int src = pair[(size_t)e * 2 + 1];

    const float4* up = (const float4*)(U + (size_t)src * UPITCH + lane * 16);
    const float4* bp = (const float4*)(bond + (size_t)e * BDIM);

    float4 u0 = up[0], u1 = up[1], u2 = up[2], u3 = up[3];
    float4 b0 = bp[0], b1 = bp[1], b2 = bp[2], b3 = bp[3];

    float m;
    m  = u0.x * b0.x;
    m  = fmaf(u0.y, b0.y, m);
    m  = fmaf(u0.z, b0.z, m);
    m  = fmaf(u0.w, b0.w, m);
    m  = fmaf(u1.x, b1.x, m);
    m  = fmaf(u1.y, b1.y, m);
    m  = fmaf(u1.z, b1.z, m);
    m  = fmaf(u1.w, b1.w, m);
    m  = fmaf(u2.x, b2.x, m);
    m  = fmaf(u2.y, b2.y, m);
    m  = fmaf(u2.z, b2.z, m);
    m  = fmaf(u2.w, b2.w, m);
    m  = fmaf(u3.x, b3.x, m);
    m  = fmaf(u3.y, b3.y, m);
    m  = fmaf(u3.z, b3.z, m);
    m  = fmaf(u3.w, b3.w, m);

    // bias contribution: U col 1024 + i
    m += U[(size_t)src * UPITCH + 1024 + lane];

    atomicAdd(out + (size_t)dst * ADIM + lane, m);
}

extern "C" void kernel_launch(void* const* d_in, const int* in_sizes, int n_in,
                              void* d_out, int out_size, void* d_ws, size_t ws_size,
                              hipStream_t stream) {
    const float* atom = (const float*)d_in[0];   // [4480, 64]  f32
    const float* bond = (const float*)d_in[1];   // [65536, 16] f32
    const int*   pair = (const int*)  d_in[2];   // [65536, 2]  int32 (JAX demotes int64)
    const float* kern = (const float*)d_in[3];   // [16, 4096]  f32
    const float* bias = (const float*)d_in[4];   // [4096]      f32

    float* out = (float*)d_out;                  // [4480, 64]  f32
    float* U   = (float*)d_ws;                   // [4480, 1088] f32 = 19.5 MB

    // out is poisoned with 0xAA before every timed launch -> zero it.
    hipMemsetAsync(out, 0, (size_t)NSEG * ADIM * sizeof(float), stream);

    dim3 g1(NSEG / 64, UPITCH / 64);             // 70 x 17 tiles
    proj_kernel<<<g1, 256, 0, stream>>>(atom, kern, bias, U);

    edge_kernel<<<NEDGE / 4, 256, 0, stream>>>(bond, pair, U, out);
}